// Round 2
// baseline (247.282 us; speedup 1.0000x reference)
//
#include <hip/hip_runtime.h>

// IoU assigner: N anchors x M gts (3D, 6 coords). Outputs (concatenated, f32):
//   out[0:N]   labels (-1 ignore, 0 neg, gt_label pos)
//   out[N:7N]  assigned boxes (gt box if pos, else -1.0)
//
// Bit-exact vs numpy f32: __f*_rn intrinsics (no FMA contraction), op order
// mirrors the jnp reference; argmax ties: first index (strict > scan).
//
// ws layout: [0,4096) gtw[M][8] = {x0,y0,z0,x1,y1,z1,area,label_f}
//            [4096, 4096+1024) slots[M] u64 = (iou_bits<<32)|(~anchor)
//            [5120, 5124) ticket counter

#define MMAX 128

__global__ __launch_bounds__(MMAX) void iou_prep(
    const float* __restrict__ gt, const int* __restrict__ gl,
    float* __restrict__ gtw, unsigned long long* __restrict__ slots,
    unsigned int* __restrict__ counter, int M)
{
    const int i = threadIdx.x;
    if (i < M) {
        const float* gp = gt + (size_t)i * 6;
        float x0 = gp[0], y0 = gp[1], z0 = gp[2];
        float x1 = gp[3], y1 = gp[4], z1 = gp[5];
        float area = __fmul_rn(__fmul_rn(__fsub_rn(x1, x0), __fsub_rn(y1, y0)),
                               __fsub_rn(z1, z0));
        float* w = gtw + i * 8;
        w[0] = x0; w[1] = y0; w[2] = z0; w[3] = x1; w[4] = y1; w[5] = z1;
        w[6] = area; w[7] = (float)gl[i];
        slots[i] = 0ULL;
    }
    if (i == 0) *counter = 0u;
}

template <int MC>
__global__ __launch_bounds__(256) void iou_main(
    const float* __restrict__ bx, const float* __restrict__ gtw,
    float* __restrict__ out_lab, float* __restrict__ out_bb,
    unsigned long long* __restrict__ slots, unsigned int* __restrict__ counter,
    int N, int Mrt, int nblocks)
{
    const int M = MC ? MC : Mrt;
    const int tid = threadIdx.x;
    const int a = blockIdx.x * 256 + tid;
    const bool act = (a < N);

    // Inactive lanes get a degenerate zero box -> inter is never > 0.
    float ax0 = 0.f, ay0 = 0.f, az0 = 0.f, ax1 = 0.f, ay1 = 0.f, az1 = 0.f;
    float a1 = 0.f;
    if (act) {
        const float2* p = (const float2*)(bx + (size_t)a * 6);
        float2 p0 = p[0], p1 = p[1], p2 = p[2];
        ax0 = p0.x; ay0 = p0.y; az0 = p1.x; ax1 = p1.y; ay1 = p2.x; az1 = p2.y;
        a1 = __fmul_rn(__fmul_rn(__fsub_rn(ax1, ax0), __fsub_rn(ay1, ay0)),
                       __fsub_rn(az1, az0));
    }

    // best starts at 0: iou==0 never strict-beats it, matching jnp.argmax
    // (first index of max; all-zero row -> argmax 0).
    float best = 0.0f;
    int   barg = 0;

#pragma unroll 4
    for (int g = 0; g < M; ++g) {
        const float* gp = gtw + g * 8;        // uniform index -> s_load
        float gx0 = gp[0], gy0 = gp[1], gz0 = gp[2];
        float gx1 = gp[3], gy1 = gp[4], gz1 = gp[5];
        float a2  = gp[6];
        float cx = fmaxf(__fsub_rn(fminf(ax1, gx1), fmaxf(ax0, gx0)), 0.0f);
        float cy = fmaxf(__fsub_rn(fminf(ay1, gy1), fmaxf(ay0, gy0)), 0.0f);
        float cz = fmaxf(__fsub_rn(fminf(az1, gz1), fmaxf(az0, gz0)), 0.0f);
        float inter = __fmul_rn(__fmul_rn(cx, cy), cz);
        if (inter > 0.0f) {                    // ~0.3% of lane-pairs
            float den = __fadd_rn(__fsub_rn(__fadd_rn(a1, a2), inter), 1e-7f);
            float iou = __fdiv_rn(inter, den);
            if (iou > best) { best = iou; barg = g; }
            if (iou >= 0.3f) {
                // Only ious >= MIN_POS_IOU can matter for the per-gt max:
                // slot != 0  <=>  column max >= 0.3, and then it holds the
                // exact max with smallest-anchor tie-break.
                unsigned long long enc =
                    ((unsigned long long)__float_as_uint(iou) << 32) |
                    (unsigned long long)(0xFFFFFFFFu - (unsigned)a);
                atomicMax(&slots[g], enc);
            }
        }
    }

    if (act) {
        float lab;
        float b0 = -1.f, b1 = -1.f, b2 = -1.f, b3 = -1.f, b4 = -1.f, b5 = -1.f;
        if (best >= 0.7f) {
            const float4* r = (const float4*)(gtw + (size_t)barg * 8);
            float4 lo = r[0], hi = r[1];
            lab = hi.w;
            b0 = lo.x; b1 = lo.y; b2 = lo.z; b3 = lo.w; b4 = hi.x; b5 = hi.y;
        } else {
            lab = (best < 0.3f) ? 0.0f : -1.0f;
        }
        out_lab[a] = lab;
        float2* ob = (float2*)(out_bb + (size_t)a * 6);
        ob[0] = make_float2(b0, b1);
        ob[1] = make_float2(b2, b3);
        ob[2] = make_float2(b4, b5);
    }

    // ---- last-finished block applies the low-quality override ----
    __shared__ unsigned int s_ticket;
    __threadfence();                       // my stores+atomics visible device-wide
    __syncthreads();                       // all threads fenced before ticket
    if (tid == 0) s_ticket = atomicAdd(counter, 1u);
    __syncthreads();
    if (s_ticket != (unsigned)(nblocks - 1)) return;

    __shared__ int s_anchor[MMAX];
    __shared__ int s_cand[MMAX];
    int anchor = -1, cand = 0;
    if (tid < M) {
        unsigned long long v = atomicMax(&slots[tid], 0ULL);  // coherent read
        if (v != 0ULL) {                   // gt_iou_max >= 0.3
            anchor = (int)(0xFFFFFFFFu - (unsigned)(v & 0xFFFFFFFFu));
            cand   = tid + 1;
        }
    }
    if (tid < MMAX) { s_anchor[tid] = anchor; s_cand[tid] = cand; }
    __syncthreads();
    if (cand > 0) {
        // Largest gt index targeting the same anchor wins (.at[].max scatter).
        bool win = true;
        for (int j = 0; j < M; ++j)
            if (s_cand[j] > cand && s_anchor[j] == anchor) win = false;
        if (win) {
            const float4* r = (const float4*)(gtw + (size_t)tid * 8);
            float4 lo = r[0], hi = r[1];
            out_lab[anchor] = hi.w;
            float2* ob = (float2*)(out_bb + (size_t)anchor * 6);
            ob[0] = make_float2(lo.x, lo.y);
            ob[1] = make_float2(lo.z, lo.w);
            ob[2] = make_float2(hi.x, hi.y);
        }
    }
}

extern "C" void kernel_launch(void* const* d_in, const int* in_sizes, int n_in,
                              void* d_out, int out_size, void* d_ws, size_t ws_size,
                              hipStream_t stream)
{
    const float* bx = (const float*)d_in[0];
    const float* gt = (const float*)d_in[1];
    const int*   gl = (const int*)d_in[2];
    const int N = in_sizes[0] / 6;
    int M = in_sizes[1] / 6;
    if (M > MMAX) M = MMAX;

    float* out_lab = (float*)d_out;
    float* out_bb  = (float*)d_out + N;

    float* gtw = (float*)d_ws;
    unsigned long long* slots = (unsigned long long*)((char*)d_ws + 4096);
    unsigned int* counter = (unsigned int*)((char*)d_ws + 4096 + MMAX * 8);

    const int nblocks = (N + 255) / 256;

    hipLaunchKernelGGL(iou_prep, dim3(1), dim3(MMAX), 0, stream,
                       gt, gl, gtw, slots, counter, M);
    if (M == MMAX) {
        hipLaunchKernelGGL(iou_main<MMAX>, dim3(nblocks), dim3(256), 0, stream,
                           bx, gtw, out_lab, out_bb, slots, counter, N, M, nblocks);
    } else {
        hipLaunchKernelGGL(iou_main<0>, dim3(nblocks), dim3(256), 0, stream,
                           bx, gtw, out_lab, out_bb, slots, counter, N, M, nblocks);
    }
}

// Round 3
// 132.755 us; speedup vs baseline: 1.8627x; 1.8627x over previous
//
#include <hip/hip_runtime.h>

// IoU assigner: N anchors x M gts (3D, 6 coords). Outputs (concatenated, f32):
//   out[0:N]   labels (-1 ignore, 0 neg, gt_label pos)
//   out[N:7N]  assigned boxes (gt box if pos, else -1.0)
//
// Bit-exact vs numpy f32: __f*_rn intrinsics (no FMA contraction), op order
// mirrors the jnp reference; argmax ties: first index (strict > scan).
//
// Structure: 4 anchors per thread (amortizes the per-gt LDS broadcast read
// over 4 independent IoU chains -> VALU-bound, ~12us floor), gt tile staged
// per block into LDS, per-gt max via filtered (iou>=0.3) global atomicMax on
// (iou_bits<<32)|~anchor, low-quality override fused into last-finished block.
//
// ws layout: [0,1024) slots[128] u64; [1024,1028) ticket counter.

#define MMAX 128

template <int MC>
__global__ __launch_bounds__(256) void iou_main(
    const float* __restrict__ bx, const float* __restrict__ gt,
    const int* __restrict__ gl,
    float* __restrict__ out_lab, float* __restrict__ out_bb,
    unsigned long long* __restrict__ slots, unsigned int* __restrict__ counter,
    int N, int Mrt, int nblocks)
{
    const int M = MC ? MC : Mrt;
    const int tid = threadIdx.x;

    // ---- stage gt boxes + area + label into LDS (per block) ----
    __shared__ float gb[MMAX][8];   // x0,y0,z0,x1 | y1,z1,area,label
    if (tid < M) {
        const float* gp = gt + (size_t)tid * 6;
        float x0 = gp[0], y0 = gp[1], z0 = gp[2];
        float x1 = gp[3], y1 = gp[4], z1 = gp[5];
        float area = __fmul_rn(__fmul_rn(__fsub_rn(x1, x0), __fsub_rn(y1, y0)),
                               __fsub_rn(z1, z0));
        gb[tid][0] = x0; gb[tid][1] = y0; gb[tid][2] = z0; gb[tid][3] = x1;
        gb[tid][4] = y1; gb[tid][5] = z1; gb[tid][6] = area;
        gb[tid][7] = (float)gl[tid];
    }
    __syncthreads();

    // ---- load 4 contiguous anchors (96B contiguous per thread) ----
    const long long base = ((long long)blockIdx.x * 256 + tid) * 4;
    const bool full = (base + 3 < (long long)N);

    float ax0[4], ay0[4], az0[4], ax1[4], ay1[4], az1[4], a1[4];
    if (full) {
        const float4* p = (const float4*)(bx + base * 6);
        float4 q0 = p[0], q1 = p[1], q2 = p[2], q3 = p[3], q4 = p[4], q5 = p[5];
        ax0[0]=q0.x; ay0[0]=q0.y; az0[0]=q0.z; ax1[0]=q0.w; ay1[0]=q1.x; az1[0]=q1.y;
        ax0[1]=q1.z; ay0[1]=q1.w; az0[1]=q2.x; ax1[1]=q2.y; ay1[1]=q2.z; az1[1]=q2.w;
        ax0[2]=q3.x; ay0[2]=q3.y; az0[2]=q3.z; ax1[2]=q3.w; ay1[2]=q4.x; az1[2]=q4.y;
        ax0[3]=q4.z; ay0[3]=q4.w; az0[3]=q5.x; ax1[3]=q5.y; ay1[3]=q5.z; az1[3]=q5.w;
    } else {
#pragma unroll
        for (int k = 0; k < 4; ++k) {
            long long a = base + k;
            if (a < (long long)N) {
                const float* p = bx + a * 6;
                ax0[k]=p[0]; ay0[k]=p[1]; az0[k]=p[2];
                ax1[k]=p[3]; ay1[k]=p[4]; az1[k]=p[5];
            } else {
                // degenerate zero box: inter never > 0, never stores
                ax0[k]=ay0[k]=az0[k]=ax1[k]=ay1[k]=az1[k]=0.f;
            }
        }
    }
#pragma unroll
    for (int k = 0; k < 4; ++k)
        a1[k] = __fmul_rn(__fmul_rn(__fsub_rn(ax1[k], ax0[k]),
                                    __fsub_rn(ay1[k], ay0[k])),
                          __fsub_rn(az1[k], az0[k]));

    // best=0: iou==0 never strict-beats it (matches jnp.argmax first-index,
    // all-zero row -> argmax 0).
    float best[4] = {0.f, 0.f, 0.f, 0.f};
    int   barg[4] = {0, 0, 0, 0};

#pragma unroll 2
    for (int g = 0; g < M; ++g) {
        const float4 lo = *(const float4*)&gb[g][0];  // x0,y0,z0,x1 (broadcast)
        const float4 hi = *(const float4*)&gb[g][4];  // y1,z1,area,label
#pragma unroll
        for (int k = 0; k < 4; ++k) {
            float cx = fmaxf(__fsub_rn(fminf(ax1[k], lo.w), fmaxf(ax0[k], lo.x)), 0.f);
            float cy = fmaxf(__fsub_rn(fminf(ay1[k], hi.x), fmaxf(ay0[k], lo.y)), 0.f);
            float cz = fmaxf(__fsub_rn(fminf(az1[k], hi.y), fmaxf(az0[k], lo.z)), 0.f);
            float inter = __fmul_rn(__fmul_rn(cx, cy), cz);
            if (inter > 0.f) {                  // ~0.3% of lane-pairs
                float den = __fadd_rn(__fsub_rn(__fadd_rn(a1[k], hi.z), inter), 1e-7f);
                float iou = __fdiv_rn(inter, den);
                if (iou > best[k]) { best[k] = iou; barg[k] = g; }
                if (iou >= 0.3f) {
                    // slot != 0 <=> column max >= MIN_POS_IOU; then it holds
                    // the exact max, smallest-anchor tie-break via ~anchor.
                    unsigned long long enc =
                        ((unsigned long long)__float_as_uint(iou) << 32) |
                        (unsigned long long)(0xFFFFFFFFu - (unsigned)(base + k));
                    atomicMax(&slots[g], enc);
                }
            }
        }
    }

    // ---- write labels + boxes (vectorized when all 4 anchors valid) ----
    float lab[4];
#pragma unroll
    for (int k = 0; k < 4; ++k) {
        if (best[k] >= 0.7f) lab[k] = gb[barg[k]][7];
        else                 lab[k] = (best[k] < 0.3f) ? 0.f : -1.f;
    }

    if (full) {
        *(float4*)(out_lab + base) = make_float4(lab[0], lab[1], lab[2], lab[3]);
        float bo[24];
#pragma unroll
        for (int k = 0; k < 4; ++k) {
            bool pos = (best[k] >= 0.7f);
            float4 l2 = *(const float4*)&gb[barg[k]][0];
            float4 h2 = *(const float4*)&gb[barg[k]][4];
            bo[k*6+0] = pos ? l2.x : -1.f;
            bo[k*6+1] = pos ? l2.y : -1.f;
            bo[k*6+2] = pos ? l2.z : -1.f;
            bo[k*6+3] = pos ? l2.w : -1.f;
            bo[k*6+4] = pos ? h2.x : -1.f;
            bo[k*6+5] = pos ? h2.y : -1.f;
        }
        float4* ob = (float4*)(out_bb + base * 6);
#pragma unroll
        for (int j = 0; j < 6; ++j)
            ob[j] = make_float4(bo[j*4], bo[j*4+1], bo[j*4+2], bo[j*4+3]);
    } else {
#pragma unroll
        for (int k = 0; k < 4; ++k) {
            long long a = base + k;
            if (a < (long long)N) {
                out_lab[a] = lab[k];
                bool pos = (best[k] >= 0.7f);
                float4 l2 = *(const float4*)&gb[barg[k]][0];
                float4 h2 = *(const float4*)&gb[barg[k]][4];
                float* ob = out_bb + a * 6;
                ob[0] = pos ? l2.x : -1.f; ob[1] = pos ? l2.y : -1.f;
                ob[2] = pos ? l2.z : -1.f; ob[3] = pos ? l2.w : -1.f;
                ob[4] = pos ? h2.x : -1.f; ob[5] = pos ? h2.y : -1.f;
            }
        }
    }

    // ---- last-finished block applies the low-quality override ----
    __shared__ unsigned int s_ticket;
    __threadfence();                   // stores+atomics visible device-wide
    __syncthreads();
    if (tid == 0) s_ticket = atomicAdd(counter, 1u);
    __syncthreads();
    if (s_ticket != (unsigned)(nblocks - 1)) return;

    __shared__ int s_anchor[MMAX];
    __shared__ int s_cand[MMAX];
    int anchor = -1, cand = 0;
    if (tid < M) {
        unsigned long long v = atomicMax(&slots[tid], 0ULL);   // coherent read
        if (v != 0ULL) {               // gt_iou_max >= 0.3
            anchor = (int)(0xFFFFFFFFu - (unsigned)(v & 0xFFFFFFFFu));
            cand   = tid + 1;
        }
    }
    if (tid < MMAX) { s_anchor[tid] = anchor; s_cand[tid] = cand; }
    __syncthreads();
    if (cand > 0) {
        // Largest gt index targeting the same anchor wins (.at[].max scatter).
        bool win = true;
        for (int j = 0; j < M; ++j)
            if (s_cand[j] > cand && s_anchor[j] == anchor) win = false;
        if (win) {
            out_lab[anchor] = gb[tid][7];
            float* ob = out_bb + (size_t)anchor * 6;
            ob[0] = gb[tid][0]; ob[1] = gb[tid][1]; ob[2] = gb[tid][2];
            ob[3] = gb[tid][3]; ob[4] = gb[tid][4]; ob[5] = gb[tid][5];
        }
    }
}

extern "C" void kernel_launch(void* const* d_in, const int* in_sizes, int n_in,
                              void* d_out, int out_size, void* d_ws, size_t ws_size,
                              hipStream_t stream)
{
    const float* bx = (const float*)d_in[0];
    const float* gt = (const float*)d_in[1];
    const int*   gl = (const int*)d_in[2];
    const int N = in_sizes[0] / 6;
    int M = in_sizes[1] / 6;
    if (M > MMAX) M = MMAX;

    float* out_lab = (float*)d_out;
    float* out_bb  = (float*)d_out + N;

    unsigned long long* slots = (unsigned long long*)d_ws;
    unsigned int* counter = (unsigned int*)((char*)d_ws + MMAX * 8);

    // slots + counter must be zeroed every call (ws is poisoned once, not
    // re-poisoned between timed replays).
    hipMemsetAsync(d_ws, 0, MMAX * 8 + 16, stream);

    const int threads_total = (N + 3) / 4;
    const int nblocks = (threads_total + 255) / 256;

    if (M == MMAX) {
        hipLaunchKernelGGL(iou_main<MMAX>, dim3(nblocks), dim3(256), 0, stream,
                           bx, gt, gl, out_lab, out_bb, slots, counter, N, M, nblocks);
    } else {
        hipLaunchKernelGGL(iou_main<0>, dim3(nblocks), dim3(256), 0, stream,
                           bx, gt, gl, out_lab, out_bb, slots, counter, N, M, nblocks);
    }
}

// Round 4
// 132.256 us; speedup vs baseline: 1.8697x; 1.0038x over previous
//
#include <hip/hip_runtime.h>

// IoU assigner: N anchors x M gts (3D, 6 coords). Outputs (concatenated, f32):
//   out[0:N]   labels (-1 ignore, 0 neg, gt_label pos)
//   out[N:7N]  assigned boxes (gt box if pos, else -1.0)
//
// Bit-exact vs numpy f32: __f*_rn intrinsics (no FMA contraction), op order
// mirrors the jnp reference; argmax ties: first index (strict > scan).
//
// Structure: 4 anchors per thread, ALL per-thread state in named scalars
// (round-3 regression: arrays -> scratch, VGPR=40, 11% issue). gt tile in
// LDS, software-pipelined broadcast read (prefetch g+1 while computing g).
// Per-gt column max via filtered (iou>=0.3) global atomicMax on
// (iou_bits<<32)|~anchor; low-quality override fused into last-finished block.
//
// ws layout: [0,1024) slots[128] u64; [1024,1028) ticket counter.

#define MMAX 128

// One anchor's IoU-vs-gt(g) step. glo = {x0,y0,z0,x1}, ghi = {y1,z1,area,label}.
#define IOU_K(AX0, AY0, AZ0, AX1, AY1, AZ1, A1, BEST, BARG, IDX)               \
    {                                                                          \
        float cx = fmaxf(__fsub_rn(fminf(AX1, glo.w), fmaxf(AX0, glo.x)), 0.f);\
        float cy = fmaxf(__fsub_rn(fminf(AY1, ghi.x), fmaxf(AY0, glo.y)), 0.f);\
        float cz = fmaxf(__fsub_rn(fminf(AZ1, ghi.y), fmaxf(AZ0, glo.z)), 0.f);\
        float inter = __fmul_rn(__fmul_rn(cx, cy), cz);                        \
        if (inter > 0.f) { /* ~0.3% of pairs */                                \
            float den = __fadd_rn(__fsub_rn(__fadd_rn(A1, ghi.z), inter), 1e-7f);\
            float iou = __fdiv_rn(inter, den);                                 \
            if (iou > BEST) { BEST = iou; BARG = g; }                          \
            if (iou >= 0.3f) {                                                 \
                unsigned long long enc =                                       \
                    ((unsigned long long)__float_as_uint(iou) << 32) |         \
                    (unsigned long long)(0xFFFFFFFFu - (unsigned)(IDX));       \
                atomicMax(&slots[g], enc);                                     \
            }                                                                  \
        }                                                                      \
    }

template <int MC>
__global__ __launch_bounds__(256) void iou_main(
    const float* __restrict__ bx, const float* __restrict__ gt,
    const int* __restrict__ gl,
    float* __restrict__ out_lab, float* __restrict__ out_bb,
    unsigned long long* __restrict__ slots, unsigned int* __restrict__ counter,
    int N, int Mrt, int nblocks)
{
    const int M = MC ? MC : Mrt;
    const int tid = threadIdx.x;

    // ---- stage gt boxes + area + label into LDS (per block) ----
    __shared__ float gb[MMAX][8];   // x0,y0,z0,x1 | y1,z1,area,label
    if (tid < M) {
        const float* gp = gt + (size_t)tid * 6;
        float x0 = gp[0], y0 = gp[1], z0 = gp[2];
        float x1 = gp[3], y1 = gp[4], z1 = gp[5];
        float area = __fmul_rn(__fmul_rn(__fsub_rn(x1, x0), __fsub_rn(y1, y0)),
                               __fsub_rn(z1, z0));
        gb[tid][0] = x0; gb[tid][1] = y0; gb[tid][2] = z0; gb[tid][3] = x1;
        gb[tid][4] = y1; gb[tid][5] = z1; gb[tid][6] = area;
        gb[tid][7] = (float)gl[tid];
    }
    __syncthreads();

    // ---- load 4 contiguous anchors into NAMED scalars (96B contiguous) ----
    const long long base = ((long long)blockIdx.x * 256 + tid) * 4;
    const bool full = (base + 3 < (long long)N);

    float ax0_0, ay0_0, az0_0, ax1_0, ay1_0, az1_0;
    float ax0_1, ay0_1, az0_1, ax1_1, ay1_1, az1_1;
    float ax0_2, ay0_2, az0_2, ax1_2, ay1_2, az1_2;
    float ax0_3, ay0_3, az0_3, ax1_3, ay1_3, az1_3;

    if (full) {
        const float4* p = (const float4*)(bx + base * 6);
        float4 q0 = p[0], q1 = p[1], q2 = p[2], q3 = p[3], q4 = p[4], q5 = p[5];
        ax0_0=q0.x; ay0_0=q0.y; az0_0=q0.z; ax1_0=q0.w; ay1_0=q1.x; az1_0=q1.y;
        ax0_1=q1.z; ay0_1=q1.w; az0_1=q2.x; ax1_1=q2.y; ay1_1=q2.z; az1_1=q2.w;
        ax0_2=q3.x; ay0_2=q3.y; az0_2=q3.z; ax1_2=q3.w; ay1_2=q4.x; az1_2=q4.y;
        ax0_3=q4.z; ay0_3=q4.w; az0_3=q5.x; ax1_3=q5.y; ay1_3=q5.z; az1_3=q5.w;
    } else {
        // tail: guarded scalar loads; invalid anchors get degenerate zero box
        ax0_0=ay0_0=az0_0=ax1_0=ay1_0=az1_0=0.f;
        ax0_1=ay0_1=az0_1=ax1_1=ay1_1=az1_1=0.f;
        ax0_2=ay0_2=az0_2=ax1_2=ay1_2=az1_2=0.f;
        ax0_3=ay0_3=az0_3=ax1_3=ay1_3=az1_3=0.f;
        if (base + 0 < N) { const float* p = bx + (base+0)*6;
            ax0_0=p[0]; ay0_0=p[1]; az0_0=p[2]; ax1_0=p[3]; ay1_0=p[4]; az1_0=p[5]; }
        if (base + 1 < N) { const float* p = bx + (base+1)*6;
            ax0_1=p[0]; ay0_1=p[1]; az0_1=p[2]; ax1_1=p[3]; ay1_1=p[4]; az1_1=p[5]; }
        if (base + 2 < N) { const float* p = bx + (base+2)*6;
            ax0_2=p[0]; ay0_2=p[1]; az0_2=p[2]; ax1_2=p[3]; ay1_2=p[4]; az1_2=p[5]; }
        if (base + 3 < N) { const float* p = bx + (base+3)*6;
            ax0_3=p[0]; ay0_3=p[1]; az0_3=p[2]; ax1_3=p[3]; ay1_3=p[4]; az1_3=p[5]; }
    }

    const float a1_0 = __fmul_rn(__fmul_rn(__fsub_rn(ax1_0, ax0_0),
                        __fsub_rn(ay1_0, ay0_0)), __fsub_rn(az1_0, az0_0));
    const float a1_1 = __fmul_rn(__fmul_rn(__fsub_rn(ax1_1, ax0_1),
                        __fsub_rn(ay1_1, ay0_1)), __fsub_rn(az1_1, az0_1));
    const float a1_2 = __fmul_rn(__fmul_rn(__fsub_rn(ax1_2, ax0_2),
                        __fsub_rn(ay1_2, ay0_2)), __fsub_rn(az1_2, az0_2));
    const float a1_3 = __fmul_rn(__fmul_rn(__fsub_rn(ax1_3, ax0_3),
                        __fsub_rn(ay1_3, ay0_3)), __fsub_rn(az1_3, az0_3));

    // best=0: iou==0 never strict-beats it (matches jnp.argmax first-index,
    // all-zero row -> argmax 0).
    float best_0 = 0.f, best_1 = 0.f, best_2 = 0.f, best_3 = 0.f;
    int   barg_0 = 0,   barg_1 = 0,   barg_2 = 0,   barg_3 = 0;

    // ---- gt loop, software-pipelined LDS broadcast (prefetch g+1) ----
    float4 glo = *(const float4*)&gb[0][0];
    float4 ghi = *(const float4*)&gb[0][4];
#pragma unroll 2
    for (int g = 0; g < M; ++g) {
        const int gn = (g + 1 < M) ? (g + 1) : 0;
        const float4 nlo = *(const float4*)&gb[gn][0];
        const float4 nhi = *(const float4*)&gb[gn][4];
        IOU_K(ax0_0, ay0_0, az0_0, ax1_0, ay1_0, az1_0, a1_0, best_0, barg_0, base + 0)
        IOU_K(ax0_1, ay0_1, az0_1, ax1_1, ay1_1, az1_1, a1_1, best_1, barg_1, base + 1)
        IOU_K(ax0_2, ay0_2, az0_2, ax1_2, ay1_2, az1_2, a1_2, best_2, barg_2, base + 2)
        IOU_K(ax0_3, ay0_3, az0_3, ax1_3, ay1_3, az1_3, a1_3, best_3, barg_3, base + 3)
        glo = nlo; ghi = nhi;
    }

    // ---- epilogue: labels + boxes, all named scalars ----
    const bool p0 = best_0 >= 0.7f, p1 = best_1 >= 0.7f,
               p2 = best_2 >= 0.7f, p3 = best_3 >= 0.7f;
    const float4 l0 = *(const float4*)&gb[barg_0][0], h0 = *(const float4*)&gb[barg_0][4];
    const float4 l1 = *(const float4*)&gb[barg_1][0], h1 = *(const float4*)&gb[barg_1][4];
    const float4 l2 = *(const float4*)&gb[barg_2][0], h2 = *(const float4*)&gb[barg_2][4];
    const float4 l3 = *(const float4*)&gb[barg_3][0], h3 = *(const float4*)&gb[barg_3][4];

    const float lab0 = p0 ? h0.w : (best_0 < 0.3f ? 0.f : -1.f);
    const float lab1 = p1 ? h1.w : (best_1 < 0.3f ? 0.f : -1.f);
    const float lab2 = p2 ? h2.w : (best_2 < 0.3f ? 0.f : -1.f);
    const float lab3 = p3 ? h3.w : (best_3 < 0.3f ? 0.f : -1.f);

    if (full) {
        *(float4*)(out_lab + base) = make_float4(lab0, lab1, lab2, lab3);
        float4* ob = (float4*)(out_bb + base * 6);
        ob[0] = make_float4(p0 ? l0.x : -1.f, p0 ? l0.y : -1.f,
                            p0 ? l0.z : -1.f, p0 ? l0.w : -1.f);
        ob[1] = make_float4(p0 ? h0.x : -1.f, p0 ? h0.y : -1.f,
                            p1 ? l1.x : -1.f, p1 ? l1.y : -1.f);
        ob[2] = make_float4(p1 ? l1.z : -1.f, p1 ? l1.w : -1.f,
                            p1 ? h1.x : -1.f, p1 ? h1.y : -1.f);
        ob[3] = make_float4(p2 ? l2.x : -1.f, p2 ? l2.y : -1.f,
                            p2 ? l2.z : -1.f, p2 ? l2.w : -1.f);
        ob[4] = make_float4(p2 ? h2.x : -1.f, p2 ? h2.y : -1.f,
                            p3 ? l3.x : -1.f, p3 ? l3.y : -1.f);
        ob[5] = make_float4(p3 ? l3.z : -1.f, p3 ? l3.w : -1.f,
                            p3 ? h3.x : -1.f, p3 ? h3.y : -1.f);
    } else {
        if (base + 0 < N) { out_lab[base+0] = lab0; float* ob = out_bb + (base+0)*6;
            ob[0]=p0?l0.x:-1.f; ob[1]=p0?l0.y:-1.f; ob[2]=p0?l0.z:-1.f;
            ob[3]=p0?l0.w:-1.f; ob[4]=p0?h0.x:-1.f; ob[5]=p0?h0.y:-1.f; }
        if (base + 1 < N) { out_lab[base+1] = lab1; float* ob = out_bb + (base+1)*6;
            ob[0]=p1?l1.x:-1.f; ob[1]=p1?l1.y:-1.f; ob[2]=p1?l1.z:-1.f;
            ob[3]=p1?l1.w:-1.f; ob[4]=p1?h1.x:-1.f; ob[5]=p1?h1.y:-1.f; }
        if (base + 2 < N) { out_lab[base+2] = lab2; float* ob = out_bb + (base+2)*6;
            ob[0]=p2?l2.x:-1.f; ob[1]=p2?l2.y:-1.f; ob[2]=p2?l2.z:-1.f;
            ob[3]=p2?l2.w:-1.f; ob[4]=p2?h2.x:-1.f; ob[5]=p2?h2.y:-1.f; }
        if (base + 3 < N) { out_lab[base+3] = lab3; float* ob = out_bb + (base+3)*6;
            ob[0]=p3?l3.x:-1.f; ob[1]=p3?l3.y:-1.f; ob[2]=p3?l3.z:-1.f;
            ob[3]=p3?l3.w:-1.f; ob[4]=p3?h3.x:-1.f; ob[5]=p3?h3.y:-1.f; }
    }

    // ---- last-finished block applies the low-quality override ----
    __shared__ unsigned int s_ticket;
    __threadfence();                   // stores+atomics visible device-wide
    __syncthreads();
    if (tid == 0) s_ticket = atomicAdd(counter, 1u);
    __syncthreads();
    if (s_ticket != (unsigned)(nblocks - 1)) return;

    __shared__ int s_anchor[MMAX];
    __shared__ int s_cand[MMAX];
    int anchor = -1, cand = 0;
    if (tid < M) {
        unsigned long long v = atomicMax(&slots[tid], 0ULL);   // coherent read
        if (v != 0ULL) {               // gt_iou_max >= 0.3
            anchor = (int)(0xFFFFFFFFu - (unsigned)(v & 0xFFFFFFFFu));
            cand   = tid + 1;
        }
    }
    if (tid < MMAX) { s_anchor[tid] = anchor; s_cand[tid] = cand; }
    __syncthreads();
    if (cand > 0) {
        // Largest gt index targeting the same anchor wins (.at[].max scatter).
        bool win = true;
        for (int j = 0; j < M; ++j)
            if (s_cand[j] > cand && s_anchor[j] == anchor) win = false;
        if (win) {
            out_lab[anchor] = gb[tid][7];
            float* ob = out_bb + (size_t)anchor * 6;
            ob[0] = gb[tid][0]; ob[1] = gb[tid][1]; ob[2] = gb[tid][2];
            ob[3] = gb[tid][3]; ob[4] = gb[tid][4]; ob[5] = gb[tid][5];
        }
    }
}

extern "C" void kernel_launch(void* const* d_in, const int* in_sizes, int n_in,
                              void* d_out, int out_size, void* d_ws, size_t ws_size,
                              hipStream_t stream)
{
    const float* bx = (const float*)d_in[0];
    const float* gt = (const float*)d_in[1];
    const int*   gl = (const int*)d_in[2];
    const int N = in_sizes[0] / 6;
    int M = in_sizes[1] / 6;
    if (M > MMAX) M = MMAX;

    float* out_lab = (float*)d_out;
    float* out_bb  = (float*)d_out + N;

    unsigned long long* slots = (unsigned long long*)d_ws;
    unsigned int* counter = (unsigned int*)((char*)d_ws + MMAX * 8);

    // counter MUST be re-zeroed every call (ws is poisoned once, not
    // re-poisoned between timed replays); slots zeroing keeps runs identical.
    hipMemsetAsync(d_ws, 0, MMAX * 8 + 16, stream);

    const int threads_total = (N + 3) / 4;
    const int nblocks = (threads_total + 255) / 256;

    if (M == MMAX) {
        hipLaunchKernelGGL(iou_main<MMAX>, dim3(nblocks), dim3(256), 0, stream,
                           bx, gt, gl, out_lab, out_bb, slots, counter, N, M, nblocks);
    } else {
        hipLaunchKernelGGL(iou_main<0>, dim3(nblocks), dim3(256), 0, stream,
                           bx, gt, gl, out_lab, out_bb, slots, counter, N, M, nblocks);
    }
}